// Round 5
// baseline (303.550 us; speedup 1.0000x reference)
//
#include <hip/hip_runtime.h>

typedef unsigned short u16;
typedef unsigned int   u32;
typedef __bf16 bf16x8 __attribute__((ext_vector_type(8)));
typedef float  f32x4  __attribute__((ext_vector_type(4)));

// ---------- helpers ----------
__device__ __forceinline__ u16 f2bf(float f) {            // RNE fp32 -> bf16
    u32 x = __builtin_bit_cast(u32, f);
    x += 0x7fffu + ((x >> 16) & 1u);
    return (u16)(x >> 16);
}
__device__ __forceinline__ float bflo(u32 u) { return __builtin_bit_cast(float, u << 16); }
__device__ __forceinline__ float bfhi(u32 u) { return __builtin_bit_cast(float, u & 0xffff0000u); }

__device__ __forceinline__ bf16x8 ld_frag(const u16* p) { // 16B LDS read
    return __builtin_bit_cast(bf16x8, *(const uint4*)p);
}

__device__ __forceinline__ f32x4 mfma16(bf16x8 a, bf16x8 b, f32x4 c) {
    return __builtin_amdgcn_mfma_f32_16x16x32_bf16(a, b, c, 0, 0, 0);
}

__device__ __forceinline__ void gl_lds16(const u16* g, u16* l) {
#if __has_builtin(__builtin_amdgcn_global_load_lds)
    __builtin_amdgcn_global_load_lds(
        (__attribute__((address_space(1))) const void*)g,
        (__attribute__((address_space(3))) void*)l, 16, 0, 0);
#else
    *(uint4*)l = *(const uint4*)g;
#endif
}

// flat-thread 32x32 transpose tile, fp32 in -> bf16 out
__device__ __forceinline__ void tr_f2b(const float* __restrict__ in, u16* __restrict__ out,
                                       int R, int C, int c0, int r0, float (*t)[33], int tid) {
    int tx = tid & 31, ty = tid >> 5;
    for (int i = ty; i < 32; i += 8)
        t[i][tx] = in[(size_t)(r0 + i) * C + c0 + tx];
    __syncthreads();
    for (int i = ty; i < 32; i += 8)
        out[(size_t)(c0 + i) * R + r0 + tx] = f2bf(t[tx][i]);
}

// ---------- merged prep: x cast + wq/wk/wv transposes ----------
__global__ __launch_bounds__(256) void prep(const float* __restrict__ x,
                                            const float* __restrict__ wq,
                                            const float* __restrict__ wk,
                                            const float* __restrict__ wv,
                                            u16* xb, u16* wqT, u16* wkT, u16* wvT) {
    __shared__ float t[32][33];
    int bx = blockIdx.x, tid = threadIdx.x;
    if (bx < 4096) {                         // x: 1M float4 -> bf16
        int i = bx * 256 + tid;
        float4 v = ((const float4*)x)[i];
        u32 a = (u32)f2bf(v.x) | ((u32)f2bf(v.y) << 16);
        u32 b = (u32)f2bf(v.z) | ((u32)f2bf(v.w) << 16);
        ((uint2*)xb)[i] = make_uint2(a, b);
    } else if (bx < 8192) {                  // wq 2048x2048
        int b = bx - 4096;
        tr_f2b(wq, wqT, 2048, 2048, (b & 63) * 32, (b >> 6) * 32, t, tid);
    } else if (bx < 9216) {                  // wk 2048x512
        int b = bx - 8192;
        tr_f2b(wk, wkT, 2048, 512, (b & 15) * 32, (b >> 4) * 32, t, tid);
    } else {                                 // wv 2048x512
        int b = bx - 9216;
        tr_f2b(wv, wvT, 2048, 512, (b & 15) * 32, (b >> 4) * 32, t, tid);
    }
}

// ---------- m97-style bf16 GEMM core: Cb[M,N](bf16) = A[M,*] * BT[N,*]^T over k[ks,ke) ----------
__device__ __forceinline__ void gemm_core(const u16* __restrict__ A, const u16* __restrict__ BT,
                                          u16* Cb, int m0, int n0, int N, int Kstride,
                                          int ks, int ke) {
    __shared__ __align__(16) u16 As[128 * 32];
    __shared__ __align__(16) u16 Bs[128 * 32];
    const int tid = threadIdx.x, wave = tid >> 6, lane = tid & 63;
    const int quad = lane >> 4, l15 = lane & 15;
    const int wr = wave >> 1, wc = wave & 1;        // 64x64 per wave
    f32x4 acc[4][4] = {};
    for (int k0 = ks; k0 < ke; k0 += 32) {
        const u16* Ag = A + (size_t)m0 * Kstride + k0;
        const u16* Bg = BT + (size_t)n0 * Kstride + k0;
#pragma unroll
        for (int r2 = 0; r2 < 2; r2++) {
            int i = r2 * 256 + tid;                  // 16B chunk id; 4 chunks/row (BK=32)
            gl_lds16(Ag + (size_t)(i >> 2) * Kstride + (i & 3) * 8, &As[i * 8]);
            gl_lds16(Bg + (size_t)(i >> 2) * Kstride + (i & 3) * 8, &Bs[i * 8]);
        }
        __syncthreads();
        bf16x8 af[4], bfr[4];
#pragma unroll
        for (int i = 0; i < 4; i++) {
            af[i]  = ld_frag(&As[(wr * 64 + i * 16 + l15) * 32 + quad * 8]);
            bfr[i] = ld_frag(&Bs[(wc * 64 + i * 16 + l15) * 32 + quad * 8]);
        }
#pragma unroll
        for (int i = 0; i < 4; i++)
#pragma unroll
            for (int j = 0; j < 4; j++)
                acc[i][j] = mfma16(af[i], bfr[j], acc[i][j]);
        __syncthreads();
    }
#pragma unroll
    for (int i = 0; i < 4; i++)
#pragma unroll
        for (int r = 0; r < 4; r++) {
            u16* p = Cb + (size_t)(m0 + wr * 64 + i * 16 + quad * 4 + r) * N + n0 + wc * 64 + l15;
#pragma unroll
            for (int j = 0; j < 4; j++) p[j * 16] = f2bf(acc[i][j][r]);
        }
}

// fused Q/K/V projection, split-K=2: bf16 partials per z
__global__ __launch_bounds__(256) void gemm_proj(const u16* __restrict__ A,
                                                 const u16* __restrict__ wqT,
                                                 const u16* __restrict__ wkT,
                                                 const u16* __restrict__ wvT,
                                                 u16* Qp, u16* Kp, u16* Vp) {
    int bx = blockIdx.x, m0 = blockIdx.y * 128, z = blockIdx.z;
    int ks = z * 1024, ke = ks + 1024;
    if (bx < 16)      gemm_core(A, wqT, Qp + (size_t)z * 4194304, m0, bx * 128, 2048, 2048, ks, ke);
    else if (bx < 20) gemm_core(A, wkT, Kp + (size_t)z * 1048576, m0, (bx - 16) * 128, 512, 2048, ks, ke);
    else              gemm_core(A, wvT, Vp + (size_t)z * 1048576, m0, (bx - 20) * 128, 512, 2048, ks, ke);
}

// ---------- merged: Q partial merge + K/V partial merge + RoPE + wo transpose ----------
__global__ __launch_bounds__(256) void rope_combine(const u16* __restrict__ Qp,
                                                    const u16* __restrict__ Kp,
                                                    const u16* __restrict__ Vp,
                                                    const float* __restrict__ tc,
                                                    const float* __restrict__ tsn,
                                                    const float* __restrict__ wo,
                                                    u16* Qb, u16* Kb, u16* Vb, u16* woT) {
    __shared__ float t[32][33];
    int bx = blockIdx.x, tid = threadIdx.x;
    if (bx < 4096) {                         // Q: merge 2 bf16 partials (uint2 = 4 vals)
        int i = bx * 256 + tid;
        uint2 a = ((const uint2*)Qp)[i];
        uint2 b = ((const uint2*)(Qp + 4194304))[i];
        u32 r0_ = (u32)f2bf(bflo(a.x) + bflo(b.x)) | ((u32)f2bf(bfhi(a.x) + bfhi(b.x)) << 16);
        u32 r1_ = (u32)f2bf(bflo(a.y) + bflo(b.y)) | ((u32)f2bf(bfhi(a.y) + bfhi(b.y)) << 16);
        ((uint2*)Qb)[i] = make_uint2(r0_, r1_);
    } else if (bx < 6144) {                  // K: merge + rope -> bf16
        int s = bx - 4096, pr = tid, tt = pr & 31;
        float c = tc[s * 32 + tt], sn = tsn[s * 32 + tt];
        u32 a = ((const u32*)Kp)[s * 256 + pr];
        u32 b = ((const u32*)(Kp + 1048576))[s * 256 + pr];
        float e = bflo(a) + bflo(b), o = bfhi(a) + bfhi(b);
        ((u32*)Kb)[s * 256 + pr] = (u32)f2bf(e * c - o * sn) | ((u32)f2bf(e * sn + o * c) << 16);
    } else if (bx < 8192) {                  // V: merge + rope -> bf16 (row-major)
        int s = bx - 6144, pr = tid, tt = pr & 31;
        float c = tc[s * 32 + tt], sn = tsn[s * 32 + tt];
        u32 a = ((const u32*)Vp)[s * 256 + pr];
        u32 b = ((const u32*)(Vp + 1048576))[s * 256 + pr];
        float e = bflo(a) + bflo(b), o = bfhi(a) + bfhi(b);
        ((u32*)Vb)[s * 256 + pr] = (u32)f2bf(e * c - o * sn) | ((u32)f2bf(e * sn + o * c) << 16);
    } else {                                 // wo transpose 2048x2048
        int b = bx - 8192;
        tr_f2b(wo, woT, 2048, 2048, (b & 63) * 32, (b >> 6) * 32, t, tid);
    }
}

// bf16 (2048x512) -> bf16 transposed (512x2048)
__global__ __launch_bounds__(256) void transpose_b2b(const u16* __restrict__ in,
                                                     u16* __restrict__ out) {
    __shared__ u16 t[32][33];
    int tid = threadIdx.x, tx = tid & 31, ty = tid >> 5;
    int c0 = blockIdx.x * 32, r0 = blockIdx.y * 32;
    for (int i = ty; i < 32; i += 8)
        t[i][tx] = in[(size_t)(r0 + i) * 512 + c0 + tx];
    __syncthreads();
    for (int i = ty; i < 32; i += 8)
        out[(size_t)(c0 + i) * 2048 + r0 + tx] = t[tx][i];
}

// ---------- flash attention: no-max softmax, BKV=128, longest-first, reg double-buffer ----------
#define LPK 72    // K/Q LDS row stride (64+8)
#define LPV 136   // V^T / P LDS row stride (128+8)
#define T_(q,l,h) (((u32)(q) << 16) | ((u32)(l) << 8) | (u32)(h))
__device__ const u32 ATASK[48] = {
    T_(14,0,15), T_(15,0,16), T_(28,0,16), T_(29,0,16), T_(30,0,16), T_(31,0,16), T_(30,16,31), T_(31,16,32),
    T_(12,0,13), T_(13,0,14), T_(24,0,14), T_(25,0,14), T_(26,0,14), T_(27,0,14), T_(26,14,27), T_(27,14,28),
    T_(28,16,29), T_(29,16,30),
    T_(10,0,11), T_(11,0,12), T_(20,0,12), T_(21,0,12), T_(22,0,12), T_(23,0,12), T_(22,12,23), T_(23,12,24),
    T_(24,14,25), T_(25,14,26),
    T_(8,0,9), T_(9,0,10), T_(16,0,10), T_(17,0,10), T_(18,0,10), T_(19,0,10), T_(18,10,19), T_(19,10,20),
    T_(20,12,21), T_(21,12,22),
    T_(6,0,7), T_(7,0,8), T_(16,10,17), T_(17,10,18),
    T_(4,0,5), T_(5,0,6), T_(2,0,3), T_(3,0,4), T_(0,0,1), T_(1,0,2)
};

struct AttnSmem {
    u16 Ks[128 * LPK];       // [kv 0..127][d]
    u16 Vs[64 * LPV];        // [d][kv 0..127]  (V^T tile)
    u16 QPs[4 * 16 * LPV];   // Q staging in prologue; per-wave P staging in loop
};

__global__ __launch_bounds__(256) void attn_kernel(const u16* __restrict__ Qb,
                                                   const u16* __restrict__ Kb,
                                                   const u16* __restrict__ VbT,
                                                   u16* __restrict__ Yb,
                                                   float* __restrict__ Opart,
                                                   float* __restrict__ lpart) {
    __shared__ __align__(16) AttnSmem sm;
    const int tid = threadIdx.x, w = tid >> 6, lane = tid & 63;
    const int quad = lane >> 4, l15 = lane & 15;
    const int h = blockIdx.x, kvh = h >> 2;
    const u32 tk = ATASK[blockIdx.y];
    const int qt = tk >> 16, lo = (tk >> 8) & 255, hi = tk & 255;
    const bool partial = (qt >= 16);
    const int pt = partial ? ((qt - 16) * 2 + (lo != 0)) : 0;
    const int q0 = qt * 64;

    const u16* Qg = Qb + (size_t)q0 * 2048 + h * 64;
#pragma unroll
    for (int r2 = 0; r2 < 2; r2++) {
        int i = r2 * 256 + tid, row = i >> 3, c8 = (i & 7) * 8;
        *(uint4*)&sm.QPs[row * LPK + c8] = *(const uint4*)(Qg + (size_t)row * 2048 + c8);
    }
    __syncthreads();
    bf16x8 aQ0 = ld_frag(&sm.QPs[(w * 16 + l15) * LPK + quad * 8]);
    bf16x8 aQ1 = ld_frag(&sm.QPs[(w * 16 + l15) * LPK + 32 + quad * 8]);

    f32x4 O[4] = {};
    float l_acc[4] = {0.f, 0.f, 0.f, 0.f};
    u16* Ps = &sm.QPs[w * 16 * LPV];
    const int qrow = q0 + w * 16 + quad * 4;   // + r

    const u16* Kg0 = Kb + kvh * 64;
    const u16* Vg0 = VbT + (size_t)(kvh * 64) * 2048;

    uint4 kv[8];                               // register double-buffer: 4 K + 4 V chunks
    {
        const u16* Kg = Kg0 + (size_t)(lo * 64) * 512;
        const u16* Vg = Vg0 + lo * 64;
#pragma unroll
        for (int r2 = 0; r2 < 4; r2++) {
            int i = r2 * 256 + tid;
            kv[r2]     = *(const uint4*)(Kg + (size_t)(i >> 3) * 512 + (i & 7) * 8);
            kv[4 + r2] = *(const uint4*)(Vg + (size_t)(i >> 4) * 2048 + (i & 15) * 8);
        }
    }

    for (int jt = lo; jt < hi; jt += 2) {      // 128 kv rows per iteration
        const int j0 = jt * 64;
        __syncthreads();                       // LDS free (prev compute done)
#pragma unroll
        for (int r2 = 0; r2 < 4; r2++) {
            int i = r2 * 256 + tid;
            *(uint4*)&sm.Ks[(i >> 3) * LPK + (i & 7) * 8] = kv[r2];
            *(uint4*)&sm.Vs[(i >> 4) * LPV + (i & 15) * 8] = kv[4 + r2];
        }
        __syncthreads();
        if (jt + 2 < hi) {                     // prefetch next tile into registers
            const u16* Kg = Kg0 + (size_t)((jt + 2) * 64) * 512;
            const u16* Vg = Vg0 + (jt + 2) * 64;
#pragma unroll
            for (int r2 = 0; r2 < 4; r2++) {
                int i = r2 * 256 + tid;
                kv[r2]     = *(const uint4*)(Kg + (size_t)(i >> 3) * 512 + (i & 7) * 8);
                kv[4 + r2] = *(const uint4*)(Vg + (size_t)(i >> 4) * 2048 + (i & 15) * 8);
            }
        }

        f32x4 s[8];
#pragma unroll
        for (int j = 0; j < 8; j++) {
            bf16x8 b0 = ld_frag(&sm.Ks[(j * 16 + l15) * LPK + quad * 8]);
            bf16x8 b1 = ld_frag(&sm.Ks[(j * 16 + l15) * LPK + 32 + quad * 8]);
            f32x4 z = {};
            z = mfma16(aQ0, b0, z);
            z = mfma16(aQ1, b1, z);
            s[j] = z;
        }
        if (jt + 1 >= qt) {                    // diagonal: masked path (uniform branch)
#pragma unroll
            for (int j = 0; j < 8; j++)
#pragma unroll
                for (int r = 0; r < 4; r++) {
                    float p = __expf(s[j][r] * 0.125f);
                    if ((j0 + j * 16 + l15) > (qrow + r)) p = 0.f;
                    s[j][r] = p; l_acc[r] += p;
                }
        } else {                               // interior: no mask
#pragma unroll
            for (int j = 0; j < 8; j++)
#pragma unroll
                for (int r = 0; r < 4; r++) {
                    float p = __expf(s[j][r] * 0.125f);
                    s[j][r] = p; l_acc[r] += p;
                }
        }
#pragma unroll
        for (int j = 0; j < 8; j++)
#pragma unroll
            for (int r = 0; r < 4; r++)
                Ps[(quad * 4 + r) * LPV + j * 16 + l15] = f2bf(s[j][r]);
        bf16x8 aP[4];
#pragma unroll
        for (int kk = 0; kk < 4; kk++)
            aP[kk] = ld_frag(&Ps[l15 * LPV + kk * 32 + quad * 8]);
#pragma unroll
        for (int j = 0; j < 4; j++)
#pragma unroll
            for (int kk = 0; kk < 4; kk++) {
                bf16x8 v = ld_frag(&sm.Vs[(j * 16 + l15) * LPV + kk * 32 + quad * 8]);
                O[j] = mfma16(aP[kk], v, O[j]);
            }
    }
    float l_i[4];
#pragma unroll
    for (int r = 0; r < 4; r++) {
        float rs = l_acc[r];
        rs += __shfl_xor(rs, 1); rs += __shfl_xor(rs, 2);
        rs += __shfl_xor(rs, 4); rs += __shfl_xor(rs, 8);
        l_i[r] = rs;
    }
    if (!partial) {
#pragma unroll
        for (int r = 0; r < 4; r++) {
            float inv = __frcp_rn(l_i[r]);
#pragma unroll
            for (int j = 0; j < 4; j++)
                Yb[(size_t)(q0 + w * 16 + quad * 4 + r) * 2048 + h * 64 + j * 16 + l15] =
                    f2bf(O[j][r] * inv);
        }
    } else {
        float* Og = Opart + ((size_t)(pt * 32 + h) * 64) * 64;
#pragma unroll
        for (int r = 0; r < 4; r++) {
            int row = w * 16 + quad * 4 + r;
#pragma unroll
            for (int j = 0; j < 4; j++)
                Og[(size_t)row * 64 + j * 16 + l15] = O[j][r];
            if (l15 == 0) lpart[(size_t)(pt * 32 + h) * 64 + row] = l_i[r];
        }
    }
}

// merge the two KV-split halves for q-tiles 16..31: O=(O0+O1)/(l0+l1)
__global__ void combine_kernel(const float* __restrict__ Opart,
                               const float* __restrict__ lpart,
                               u16* __restrict__ Yb) {
    int e = blockIdx.x * 256 + threadIdx.x;       // 524288 float4 elems
    int d4 = e & 15, h = (e >> 4) & 31, rg = e >> 9;   // rg in [0,1024)
    int t16 = rg >> 6, row = rg & 63;
    int s0 = (t16 * 2) * 32 + h, s1 = s0 + 32;
    float4 a = ((const float4*)Opart)[((size_t)s0 * 64 + row) * 16 + d4];
    float4 b = ((const float4*)Opart)[((size_t)s1 * 64 + row) * 16 + d4];
    float l = lpart[(size_t)s0 * 64 + row] + lpart[(size_t)s1 * 64 + row];
    float inv = __frcp_rn(l);
    u32 lo = (u32)f2bf((a.x + b.x) * inv) | ((u32)f2bf((a.y + b.y) * inv) << 16);
    u32 hi = (u32)f2bf((a.z + b.z) * inv) | ((u32)f2bf((a.w + b.w) * inv) << 16);
    int q = 1024 + rg;
    ((uint2*)(Yb + (size_t)q * 2048 + h * 64))[d4] = make_uint2(lo, hi);
}

// final projection, split-K=4, bf16 partials (non-contiguous scratch regions)
__global__ __launch_bounds__(256) void gemm_out_split(const u16* __restrict__ A,
                                                      const u16* __restrict__ BT,
                                                      u16* C0, u16* C1, u16* C2, u16* C3) {
    int z = blockIdx.z;
    u16* dst = z == 0 ? C0 : z == 1 ? C1 : z == 2 ? C2 : C3;
    gemm_core(A, BT, dst, blockIdx.y * 128, blockIdx.x * 128, 2048, 2048, z * 512, (z + 1) * 512);
}

__global__ void combine_out(const u16* __restrict__ C0, const u16* __restrict__ C1,
                            const u16* __restrict__ C2, const u16* __restrict__ C3,
                            float* __restrict__ out) {
    int i = blockIdx.x * 256 + threadIdx.x;        // 1M uint2 (4 bf16) -> float4
    uint2 a = ((const uint2*)C0)[i], b = ((const uint2*)C1)[i];
    uint2 c = ((const uint2*)C2)[i], d = ((const uint2*)C3)[i];
    float4 o;
    o.x = bflo(a.x) + bflo(b.x) + bflo(c.x) + bflo(d.x);
    o.y = bfhi(a.x) + bfhi(b.x) + bfhi(c.x) + bfhi(d.x);
    o.z = bflo(a.y) + bflo(b.y) + bflo(c.y) + bflo(d.y);
    o.w = bfhi(a.y) + bfhi(b.y) + bfhi(c.y) + bfhi(d.y);
    ((float4*)out)[i] = o;
}

extern "C" void kernel_launch(void* const* d_in, const int* in_sizes, int n_in,
                              void* d_out, int out_size, void* d_ws, size_t ws_size,
                              hipStream_t stream) {
    const float* x  = (const float*)d_in[0];
    const float* tc = (const float*)d_in[1];
    const float* ts = (const float*)d_in[2];
    const float* wq = (const float*)d_in[3];
    const float* wk = (const float*)d_in[4];
    const float* wv = (const float*)d_in[5];
    const float* wo = (const float*)d_in[6];
    float* out = (float*)d_out;

    char* w = (char*)d_ws;
    // Phase map (48 MiB):
    // A(prep):      xb@0-8  wqT@8-16  wkT@16-18  wvT@18-20
    // B(proj sk2):  Qp@20-36(bf16 z0/z1)  Kp@36-40  Vp@40-44
    // C(ropecomb):  Qb@0-8  woT@8-16  Kb@16-18  Vb@18-20 ; transpose: VbT@20-22
    // D(attn):      lpart@22  Yb@24-32  Opart@32-48
    // F(out sk4):   Cp z0@0-8 z1@16-24 z2@32-40 z3@40-48
    u16*   xb   = (u16*)(w);
    u16*   wqT  = (u16*)(w + (8u  << 20));
    u16*   wkT  = (u16*)(w + (16u << 20));
    u16*   wvT  = (u16*)(w + (18u << 20));
    u16*   Qp   = (u16*)(w + (20u << 20));
    u16*   Kp   = (u16*)(w + (36u << 20));
    u16*   Vp   = (u16*)(w + (40u << 20));
    u16*   Qb   = (u16*)(w);
    u16*   woT  = (u16*)(w + (8u  << 20));
    u16*   Kb   = (u16*)(w + (16u << 20));
    u16*   Vb   = (u16*)(w + (18u << 20));
    u16*   VbT  = (u16*)(w + (20u << 20));
    float* lpart= (float*)(w + (22u << 20));
    u16*   Yb   = (u16*)(w + (24u << 20));
    float* Opart= (float*)(w + (32u << 20));
    u16*   C0   = (u16*)(w);
    u16*   C1   = (u16*)(w + (16u << 20));
    u16*   C2   = (u16*)(w + (32u << 20));
    u16*   C3   = (u16*)(w + (40u << 20));

    prep<<<10240, 256, 0, stream>>>(x, wq, wk, wv, xb, wqT, wkT, wvT);
    gemm_proj<<<dim3(24, 16, 2), 256, 0, stream>>>(xb, wqT, wkT, wvT, Qp, Kp, Vp);
    rope_combine<<<12288, 256, 0, stream>>>(Qp, Kp, Vp, tc, ts, wo, Qb, Kb, Vb, woT);
    transpose_b2b<<<dim3(16, 64), 256, 0, stream>>>(Vb, VbT);
    attn_kernel<<<dim3(32, 48), 256, 0, stream>>>(Qb, Kb, VbT, Yb, Opart, lpart);
    combine_kernel<<<2048, 256, 0, stream>>>(Opart, lpart, Yb);
    gemm_out_split<<<dim3(16, 16, 4), 256, 0, stream>>>(Yb, woT, C0, C1, C2, C3);
    combine_out<<<4096, 256, 0, stream>>>(C0, C1, C2, C3, out);
}

// Round 6
// 260.258 us; speedup vs baseline: 1.1663x; 1.1663x over previous
//
#include <hip/hip_runtime.h>

typedef unsigned short u16;
typedef unsigned int   u32;
typedef __bf16 bf16x8 __attribute__((ext_vector_type(8)));
typedef float  f32x4  __attribute__((ext_vector_type(4)));

// ---------- helpers ----------
__device__ __forceinline__ u16 f2bf(float f) {            // RNE fp32 -> bf16
    u32 x = __builtin_bit_cast(u32, f);
    x += 0x7fffu + ((x >> 16) & 1u);
    return (u16)(x >> 16);
}
__device__ __forceinline__ float bflo(u32 u) { return __builtin_bit_cast(float, u << 16); }
__device__ __forceinline__ float bfhi(u32 u) { return __builtin_bit_cast(float, u & 0xffff0000u); }

__device__ __forceinline__ bf16x8 ld_frag(const u16* p) { // 16B LDS read
    return __builtin_bit_cast(bf16x8, *(const uint4*)p);
}

__device__ __forceinline__ f32x4 mfma16(bf16x8 a, bf16x8 b, f32x4 c) {
    return __builtin_amdgcn_mfma_f32_16x16x32_bf16(a, b, c, 0, 0, 0);
}

__device__ __forceinline__ void gl_lds16(const u16* g, u16* l) {
#if __has_builtin(__builtin_amdgcn_global_load_lds)
    __builtin_amdgcn_global_load_lds(
        (__attribute__((address_space(1))) const void*)g,
        (__attribute__((address_space(3))) void*)l, 16, 0, 0);
#else
    *(uint4*)l = *(const uint4*)g;
#endif
}

// flat-thread 32x32 transpose tile, fp32 in -> bf16 out
__device__ __forceinline__ void tr_f2b(const float* __restrict__ in, u16* __restrict__ out,
                                       int R, int C, int c0, int r0, float (*t)[33], int tid) {
    int tx = tid & 31, ty = tid >> 5;
    for (int i = ty; i < 32; i += 8)
        t[i][tx] = in[(size_t)(r0 + i) * C + c0 + tx];
    __syncthreads();
    for (int i = ty; i < 32; i += 8)
        out[(size_t)(c0 + i) * R + r0 + tx] = f2bf(t[tx][i]);
}

// ---------- merged prep: x cast + wq/wk/wv transposes ----------
__global__ __launch_bounds__(256) void prep(const float* __restrict__ x,
                                            const float* __restrict__ wq,
                                            const float* __restrict__ wk,
                                            const float* __restrict__ wv,
                                            u16* xb, u16* wqT, u16* wkT, u16* wvT) {
    __shared__ float t[32][33];
    int bx = blockIdx.x, tid = threadIdx.x;
    if (bx < 4096) {                         // x: 1M float4 -> bf16
        int i = bx * 256 + tid;
        float4 v = ((const float4*)x)[i];
        u32 a = (u32)f2bf(v.x) | ((u32)f2bf(v.y) << 16);
        u32 b = (u32)f2bf(v.z) | ((u32)f2bf(v.w) << 16);
        ((uint2*)xb)[i] = make_uint2(a, b);
    } else if (bx < 8192) {                  // wq 2048x2048
        int b = bx - 4096;
        tr_f2b(wq, wqT, 2048, 2048, (b & 63) * 32, (b >> 6) * 32, t, tid);
    } else if (bx < 9216) {                  // wk 2048x512
        int b = bx - 8192;
        tr_f2b(wk, wkT, 2048, 512, (b & 15) * 32, (b >> 4) * 32, t, tid);
    } else {                                 // wv 2048x512
        int b = bx - 9216;
        tr_f2b(wv, wvT, 2048, 512, (b & 15) * 32, (b >> 4) * 32, t, tid);
    }
}

// ---------- m97-style bf16 GEMM core: Cb[M,N](bf16) = A[M,*] * BT[N,*]^T over k[ks,ke) ----------
__device__ __forceinline__ void gemm_core(const u16* __restrict__ A, const u16* __restrict__ BT,
                                          u16* Cb, int m0, int n0, int N, int Kstride,
                                          int ks, int ke) {
    __shared__ __align__(16) u16 As[128 * 32];
    __shared__ __align__(16) u16 Bs[128 * 32];
    const int tid = threadIdx.x, wave = tid >> 6, lane = tid & 63;
    const int quad = lane >> 4, l15 = lane & 15;
    const int wr = wave >> 1, wc = wave & 1;        // 64x64 per wave
    f32x4 acc[4][4] = {};
    for (int k0 = ks; k0 < ke; k0 += 32) {
        const u16* Ag = A + (size_t)m0 * Kstride + k0;
        const u16* Bg = BT + (size_t)n0 * Kstride + k0;
#pragma unroll
        for (int r2 = 0; r2 < 2; r2++) {
            int i = r2 * 256 + tid;                  // 16B chunk id; 4 chunks/row (BK=32)
            gl_lds16(Ag + (size_t)(i >> 2) * Kstride + (i & 3) * 8, &As[i * 8]);
            gl_lds16(Bg + (size_t)(i >> 2) * Kstride + (i & 3) * 8, &Bs[i * 8]);
        }
        __syncthreads();
        bf16x8 af[4], bfr[4];
#pragma unroll
        for (int i = 0; i < 4; i++) {
            af[i]  = ld_frag(&As[(wr * 64 + i * 16 + l15) * 32 + quad * 8]);
            bfr[i] = ld_frag(&Bs[(wc * 64 + i * 16 + l15) * 32 + quad * 8]);
        }
#pragma unroll
        for (int i = 0; i < 4; i++)
#pragma unroll
            for (int j = 0; j < 4; j++)
                acc[i][j] = mfma16(af[i], bfr[j], acc[i][j]);
        __syncthreads();
    }
#pragma unroll
    for (int i = 0; i < 4; i++)
#pragma unroll
        for (int r = 0; r < 4; r++) {
            u16* p = Cb + (size_t)(m0 + wr * 64 + i * 16 + quad * 4 + r) * N + n0 + wc * 64 + l15;
#pragma unroll
            for (int j = 0; j < 4; j++) p[j * 16] = f2bf(acc[i][j][r]);
        }
}

// fused Q/K/V projection, split-K=2: bf16 partials per z
__global__ __launch_bounds__(256) void gemm_proj(const u16* __restrict__ A,
                                                 const u16* __restrict__ wqT,
                                                 const u16* __restrict__ wkT,
                                                 const u16* __restrict__ wvT,
                                                 u16* Qp, u16* Kp, u16* Vp) {
    int bx = blockIdx.x, m0 = blockIdx.y * 128, z = blockIdx.z;
    int ks = z * 1024, ke = ks + 1024;
    if (bx < 16)      gemm_core(A, wqT, Qp + (size_t)z * 4194304, m0, bx * 128, 2048, 2048, ks, ke);
    else if (bx < 20) gemm_core(A, wkT, Kp + (size_t)z * 1048576, m0, (bx - 16) * 128, 512, 2048, ks, ke);
    else              gemm_core(A, wvT, Vp + (size_t)z * 1048576, m0, (bx - 20) * 128, 512, 2048, ks, ke);
}

// ---------- merged: Q partial merge + K/V partial merge + RoPE + wo transpose ----------
__global__ __launch_bounds__(256) void rope_combine(const u16* __restrict__ Qp,
                                                    const u16* __restrict__ Kp,
                                                    const u16* __restrict__ Vp,
                                                    const float* __restrict__ tc,
                                                    const float* __restrict__ tsn,
                                                    const float* __restrict__ wo,
                                                    u16* Qb, u16* Kb, u16* Vb, u16* woT) {
    __shared__ float t[32][33];
    int bx = blockIdx.x, tid = threadIdx.x;
    if (bx < 4096) {                         // Q: merge 2 bf16 partials (uint2 = 4 vals)
        int i = bx * 256 + tid;
        uint2 a = ((const uint2*)Qp)[i];
        uint2 b = ((const uint2*)(Qp + 4194304))[i];
        u32 r0_ = (u32)f2bf(bflo(a.x) + bflo(b.x)) | ((u32)f2bf(bfhi(a.x) + bfhi(b.x)) << 16);
        u32 r1_ = (u32)f2bf(bflo(a.y) + bflo(b.y)) | ((u32)f2bf(bfhi(a.y) + bfhi(b.y)) << 16);
        ((uint2*)Qb)[i] = make_uint2(r0_, r1_);
    } else if (bx < 6144) {                  // K: merge + rope -> bf16
        int s = bx - 4096, pr = tid, tt = pr & 31;
        float c = tc[s * 32 + tt], sn = tsn[s * 32 + tt];
        u32 a = ((const u32*)Kp)[s * 256 + pr];
        u32 b = ((const u32*)(Kp + 1048576))[s * 256 + pr];
        float e = bflo(a) + bflo(b), o = bfhi(a) + bfhi(b);
        ((u32*)Kb)[s * 256 + pr] = (u32)f2bf(e * c - o * sn) | ((u32)f2bf(e * sn + o * c) << 16);
    } else if (bx < 8192) {                  // V: merge + rope -> bf16 (row-major)
        int s = bx - 6144, pr = tid, tt = pr & 31;
        float c = tc[s * 32 + tt], sn = tsn[s * 32 + tt];
        u32 a = ((const u32*)Vp)[s * 256 + pr];
        u32 b = ((const u32*)(Vp + 1048576))[s * 256 + pr];
        float e = bflo(a) + bflo(b), o = bfhi(a) + bfhi(b);
        ((u32*)Vb)[s * 256 + pr] = (u32)f2bf(e * c - o * sn) | ((u32)f2bf(e * sn + o * c) << 16);
    } else {                                 // wo transpose 2048x2048
        int b = bx - 8192;
        tr_f2b(wo, woT, 2048, 2048, (b & 63) * 32, (b >> 6) * 32, t, tid);
    }
}

// bf16 (2048x512) -> bf16 transposed (512x2048)
__global__ __launch_bounds__(256) void transpose_b2b(const u16* __restrict__ in,
                                                     u16* __restrict__ out) {
    __shared__ u16 t[32][33];
    int tid = threadIdx.x, tx = tid & 31, ty = tid >> 5;
    int c0 = blockIdx.x * 32, r0 = blockIdx.y * 32;
    for (int i = ty; i < 32; i += 8)
        t[i][tx] = in[(size_t)(r0 + i) * 512 + c0 + tx];
    __syncthreads();
    for (int i = ty; i < 32; i += 8)
        out[(size_t)(c0 + i) * 2048 + r0 + tx] = t[tx][i];
}

// ---------- flash attention: no-max softmax, BKV=128, longest-first schedule ----------
// Staging: direct uint4 global->LDS after barrier (R4-measured structure; the R5
// register double-buffer spilled to scratch -> 280 MB WRITE_SIZE. Do not reintroduce.)
#define LPK 72    // K/Q LDS row stride (64+8)
#define LPV 136   // V^T / P LDS row stride (128+8)
#define T_(q,l,h) (((u32)(q) << 16) | ((u32)(l) << 8) | (u32)(h))
__device__ const u32 ATASK[48] = {
    T_(14,0,15), T_(15,0,16), T_(28,0,16), T_(29,0,16), T_(30,0,16), T_(31,0,16), T_(30,16,31), T_(31,16,32),
    T_(12,0,13), T_(13,0,14), T_(24,0,14), T_(25,0,14), T_(26,0,14), T_(27,0,14), T_(26,14,27), T_(27,14,28),
    T_(28,16,29), T_(29,16,30),
    T_(10,0,11), T_(11,0,12), T_(20,0,12), T_(21,0,12), T_(22,0,12), T_(23,0,12), T_(22,12,23), T_(23,12,24),
    T_(24,14,25), T_(25,14,26),
    T_(8,0,9), T_(9,0,10), T_(16,0,10), T_(17,0,10), T_(18,0,10), T_(19,0,10), T_(18,10,19), T_(19,10,20),
    T_(20,12,21), T_(21,12,22),
    T_(6,0,7), T_(7,0,8), T_(16,10,17), T_(17,10,18),
    T_(4,0,5), T_(5,0,6), T_(2,0,3), T_(3,0,4), T_(0,0,1), T_(1,0,2)
};

struct AttnSmem {
    u16 Ks[128 * LPK];       // [kv 0..127][d]
    u16 Vs[64 * LPV];        // [d][kv 0..127]  (V^T tile)
    u16 QPs[4 * 16 * LPV];   // Q staging in prologue; per-wave P staging in loop
};

__global__ __launch_bounds__(256) void attn_kernel(const u16* __restrict__ Qb,
                                                   const u16* __restrict__ Kb,
                                                   const u16* __restrict__ VbT,
                                                   u16* __restrict__ Yb,
                                                   float* __restrict__ Opart,
                                                   float* __restrict__ lpart) {
    __shared__ __align__(16) AttnSmem sm;
    const int tid = threadIdx.x, w = tid >> 6, lane = tid & 63;
    const int quad = lane >> 4, l15 = lane & 15;
    const int h = blockIdx.x, kvh = h >> 2;
    const u32 tk = ATASK[blockIdx.y];
    const int qt = tk >> 16, lo = (tk >> 8) & 255, hi = tk & 255;
    const bool partial = (qt >= 16);
    const int pt = partial ? ((qt - 16) * 2 + (lo != 0)) : 0;
    const int q0 = qt * 64;

    const u16* Qg = Qb + (size_t)q0 * 2048 + h * 64;
#pragma unroll
    for (int r2 = 0; r2 < 2; r2++) {
        int i = r2 * 256 + tid, row = i >> 3, c8 = (i & 7) * 8;
        *(uint4*)&sm.QPs[row * LPK + c8] = *(const uint4*)(Qg + (size_t)row * 2048 + c8);
    }
    __syncthreads();
    bf16x8 aQ0 = ld_frag(&sm.QPs[(w * 16 + l15) * LPK + quad * 8]);
    bf16x8 aQ1 = ld_frag(&sm.QPs[(w * 16 + l15) * LPK + 32 + quad * 8]);

    f32x4 O[4] = {};
    float l_acc[4] = {0.f, 0.f, 0.f, 0.f};
    u16* Ps = &sm.QPs[w * 16 * LPV];
    const int qrow = q0 + w * 16 + quad * 4;   // + r

    for (int jt = lo; jt < hi; jt += 2) {      // 128 kv rows per iteration
        const int j0 = jt * 64;
        __syncthreads();
        const u16* Kg = Kb + (size_t)j0 * 512 + kvh * 64;
        const u16* Vg = VbT + (size_t)(kvh * 64) * 2048 + j0;
#pragma unroll
        for (int r2 = 0; r2 < 4; r2++) {
            int i = r2 * 256 + tid;
            int krow = i >> 3, kc = (i & 7) * 8;
            *(uint4*)&sm.Ks[krow * LPK + kc] = *(const uint4*)(Kg + (size_t)krow * 512 + kc);
            int vrow = i >> 4, vc = (i & 15) * 8;
            *(uint4*)&sm.Vs[vrow * LPV + vc] = *(const uint4*)(Vg + (size_t)vrow * 2048 + vc);
        }
        __syncthreads();

        f32x4 s[8];
#pragma unroll
        for (int j = 0; j < 8; j++) {
            bf16x8 b0 = ld_frag(&sm.Ks[(j * 16 + l15) * LPK + quad * 8]);
            bf16x8 b1 = ld_frag(&sm.Ks[(j * 16 + l15) * LPK + 32 + quad * 8]);
            f32x4 z = {};
            z = mfma16(aQ0, b0, z);
            z = mfma16(aQ1, b1, z);
            s[j] = z;
        }
        if (jt + 1 >= qt) {                    // diagonal: masked path (uniform branch)
#pragma unroll
            for (int j = 0; j < 8; j++)
#pragma unroll
                for (int r = 0; r < 4; r++) {
                    float p = __expf(s[j][r] * 0.125f);
                    if ((j0 + j * 16 + l15) > (qrow + r)) p = 0.f;
                    s[j][r] = p; l_acc[r] += p;
                }
        } else {                               // interior: no mask
#pragma unroll
            for (int j = 0; j < 8; j++)
#pragma unroll
                for (int r = 0; r < 4; r++) {
                    float p = __expf(s[j][r] * 0.125f);
                    s[j][r] = p; l_acc[r] += p;
                }
        }
#pragma unroll
        for (int j = 0; j < 8; j++)
#pragma unroll
            for (int r = 0; r < 4; r++)
                Ps[(quad * 4 + r) * LPV + j * 16 + l15] = f2bf(s[j][r]);
        bf16x8 aP[4];
#pragma unroll
        for (int kk = 0; kk < 4; kk++)
            aP[kk] = ld_frag(&Ps[l15 * LPV + kk * 32 + quad * 8]);
#pragma unroll
        for (int j = 0; j < 4; j++)
#pragma unroll
            for (int kk = 0; kk < 4; kk++) {
                bf16x8 v = ld_frag(&sm.Vs[(j * 16 + l15) * LPV + kk * 32 + quad * 8]);
                O[j] = mfma16(aP[kk], v, O[j]);
            }
    }
    float l_i[4];
#pragma unroll
    for (int r = 0; r < 4; r++) {
        float rs = l_acc[r];
        rs += __shfl_xor(rs, 1); rs += __shfl_xor(rs, 2);
        rs += __shfl_xor(rs, 4); rs += __shfl_xor(rs, 8);
        l_i[r] = rs;
    }
    if (!partial) {
#pragma unroll
        for (int r = 0; r < 4; r++) {
            float inv = __frcp_rn(l_i[r]);
#pragma unroll
            for (int j = 0; j < 4; j++)
                Yb[(size_t)(q0 + w * 16 + quad * 4 + r) * 2048 + h * 64 + j * 16 + l15] =
                    f2bf(O[j][r] * inv);
        }
    } else {
        float* Og = Opart + ((size_t)(pt * 32 + h) * 64) * 64;
#pragma unroll
        for (int r = 0; r < 4; r++) {
            int row = w * 16 + quad * 4 + r;
#pragma unroll
            for (int j = 0; j < 4; j++)
                Og[(size_t)row * 64 + j * 16 + l15] = O[j][r];
            if (l15 == 0) lpart[(size_t)(pt * 32 + h) * 64 + row] = l_i[r];
        }
    }
}

// merge the two KV-split halves for q-tiles 16..31: O=(O0+O1)/(l0+l1)
__global__ void combine_kernel(const float* __restrict__ Opart,
                               const float* __restrict__ lpart,
                               u16* __restrict__ Yb) {
    int e = blockIdx.x * 256 + threadIdx.x;       // 524288 float4 elems
    int d4 = e & 15, h = (e >> 4) & 31, rg = e >> 9;   // rg in [0,1024)
    int t16 = rg >> 6, row = rg & 63;
    int s0 = (t16 * 2) * 32 + h, s1 = s0 + 32;
    float4 a = ((const float4*)Opart)[((size_t)s0 * 64 + row) * 16 + d4];
    float4 b = ((const float4*)Opart)[((size_t)s1 * 64 + row) * 16 + d4];
    float l = lpart[(size_t)s0 * 64 + row] + lpart[(size_t)s1 * 64 + row];
    float inv = __frcp_rn(l);
    u32 lo = (u32)f2bf((a.x + b.x) * inv) | ((u32)f2bf((a.y + b.y) * inv) << 16);
    u32 hi = (u32)f2bf((a.z + b.z) * inv) | ((u32)f2bf((a.w + b.w) * inv) << 16);
    int q = 1024 + rg;
    ((uint2*)(Yb + (size_t)q * 2048 + h * 64))[d4] = make_uint2(lo, hi);
}

// final projection, split-K=4, bf16 partials (non-contiguous scratch regions)
__global__ __launch_bounds__(256) void gemm_out_split(const u16* __restrict__ A,
                                                      const u16* __restrict__ BT,
                                                      u16* C0, u16* C1, u16* C2, u16* C3) {
    int z = blockIdx.z;
    u16* dst = z == 0 ? C0 : z == 1 ? C1 : z == 2 ? C2 : C3;
    gemm_core(A, BT, dst, blockIdx.y * 128, blockIdx.x * 128, 2048, 2048, z * 512, (z + 1) * 512);
}

__global__ void combine_out(const u16* __restrict__ C0, const u16* __restrict__ C1,
                            const u16* __restrict__ C2, const u16* __restrict__ C3,
                            float* __restrict__ out) {
    int i = blockIdx.x * 256 + threadIdx.x;        // 1M uint2 (4 bf16) -> float4
    uint2 a = ((const uint2*)C0)[i], b = ((const uint2*)C1)[i];
    uint2 c = ((const uint2*)C2)[i], d = ((const uint2*)C3)[i];
    float4 o;
    o.x = bflo(a.x) + bflo(b.x) + bflo(c.x) + bflo(d.x);
    o.y = bfhi(a.x) + bfhi(b.x) + bfhi(c.x) + bfhi(d.x);
    o.z = bflo(a.y) + bflo(b.y) + bflo(c.y) + bflo(d.y);
    o.w = bfhi(a.y) + bfhi(b.y) + bfhi(c.y) + bfhi(d.y);
    ((float4*)out)[i] = o;
}

extern "C" void kernel_launch(void* const* d_in, const int* in_sizes, int n_in,
                              void* d_out, int out_size, void* d_ws, size_t ws_size,
                              hipStream_t stream) {
    const float* x  = (const float*)d_in[0];
    const float* tc = (const float*)d_in[1];
    const float* ts = (const float*)d_in[2];
    const float* wq = (const float*)d_in[3];
    const float* wk = (const float*)d_in[4];
    const float* wv = (const float*)d_in[5];
    const float* wo = (const float*)d_in[6];
    float* out = (float*)d_out;

    char* w = (char*)d_ws;
    // Phase map (48 MiB):
    // A(prep):      xb@0-8  wqT@8-16  wkT@16-18  wvT@18-20
    // B(proj sk2):  Qp@20-36(bf16 z0/z1)  Kp@36-40  Vp@40-44
    // C(ropecomb):  Qb@0-8  woT@8-16  Kb@16-18  Vb@18-20 ; transpose: VbT@20-22
    // D(attn):      lpart@22  Yb@24-32  Opart@32-48
    // F(out sk4):   Cp z0@0-8 z1@16-24 z2@32-40 z3@40-48
    u16*   xb   = (u16*)(w);
    u16*   wqT  = (u16*)(w + (8u  << 20));
    u16*   wkT  = (u16*)(w + (16u << 20));
    u16*   wvT  = (u16*)(w + (18u << 20));
    u16*   Qp   = (u16*)(w + (20u << 20));
    u16*   Kp   = (u16*)(w + (36u << 20));
    u16*   Vp   = (u16*)(w + (40u << 20));
    u16*   Qb   = (u16*)(w);
    u16*   woT  = (u16*)(w + (8u  << 20));
    u16*   Kb   = (u16*)(w + (16u << 20));
    u16*   Vb   = (u16*)(w + (18u << 20));
    u16*   VbT  = (u16*)(w + (20u << 20));
    float* lpart= (float*)(w + (22u << 20));
    u16*   Yb   = (u16*)(w + (24u << 20));
    float* Opart= (float*)(w + (32u << 20));
    u16*   C0   = (u16*)(w);
    u16*   C1   = (u16*)(w + (16u << 20));
    u16*   C2   = (u16*)(w + (32u << 20));
    u16*   C3   = (u16*)(w + (40u << 20));

    prep<<<10240, 256, 0, stream>>>(x, wq, wk, wv, xb, wqT, wkT, wvT);
    gemm_proj<<<dim3(24, 16, 2), 256, 0, stream>>>(xb, wqT, wkT, wvT, Qp, Kp, Vp);
    rope_combine<<<12288, 256, 0, stream>>>(Qp, Kp, Vp, tc, ts, wo, Qb, Kb, Vb, woT);
    transpose_b2b<<<dim3(16, 64), 256, 0, stream>>>(Vb, VbT);
    attn_kernel<<<dim3(32, 48), 256, 0, stream>>>(Qb, Kb, VbT, Yb, Opart, lpart);
    combine_kernel<<<2048, 256, 0, stream>>>(Opart, lpart, Yb);
    gemm_out_split<<<dim3(16, 16, 4), 256, 0, stream>>>(Yb, woT, C0, C1, C2, C3);
    combine_out<<<4096, 256, 0, stream>>>(C0, C1, C2, C3, out);
}

// Round 7
// 250.934 us; speedup vs baseline: 1.2097x; 1.0372x over previous
//
#include <hip/hip_runtime.h>

typedef unsigned short u16;
typedef unsigned int   u32;
typedef __bf16 bf16x8 __attribute__((ext_vector_type(8)));
typedef float  f32x4  __attribute__((ext_vector_type(4)));

// ---------- helpers ----------
__device__ __forceinline__ u16 f2bf(float f) {            // RNE fp32 -> bf16
    u32 x = __builtin_bit_cast(u32, f);
    x += 0x7fffu + ((x >> 16) & 1u);
    return (u16)(x >> 16);
}
__device__ __forceinline__ float bflo(u32 u) { return __builtin_bit_cast(float, u << 16); }
__device__ __forceinline__ float bfhi(u32 u) { return __builtin_bit_cast(float, u & 0xffff0000u); }

__device__ __forceinline__ bf16x8 ld_frag(const u16* p) { // 16B LDS read
    return __builtin_bit_cast(bf16x8, *(const uint4*)p);
}

__device__ __forceinline__ f32x4 mfma16(bf16x8 a, bf16x8 b, f32x4 c) {
    return __builtin_amdgcn_mfma_f32_16x16x32_bf16(a, b, c, 0, 0, 0);
}

__device__ __forceinline__ void gl_lds16(const u16* g, u16* l) {
#if __has_builtin(__builtin_amdgcn_global_load_lds)
    __builtin_amdgcn_global_load_lds(
        (__attribute__((address_space(1))) const void*)g,
        (__attribute__((address_space(3))) void*)l, 16, 0, 0);
#else
    *(uint4*)l = *(const uint4*)g;
#endif
}

// flat-thread 32x32 transpose tile, fp32 in -> bf16 out
__device__ __forceinline__ void tr_f2b(const float* __restrict__ in, u16* __restrict__ out,
                                       int R, int C, int c0, int r0, float (*t)[33], int tid) {
    int tx = tid & 31, ty = tid >> 5;
    for (int i = ty; i < 32; i += 8)
        t[i][tx] = in[(size_t)(r0 + i) * C + c0 + tx];
    __syncthreads();
    for (int i = ty; i < 32; i += 8)
        out[(size_t)(c0 + i) * R + r0 + tx] = f2bf(t[tx][i]);
}

// ---------- merged prep: x cast + wq/wk/wv transposes ----------
__global__ __launch_bounds__(256) void prep(const float* __restrict__ x,
                                            const float* __restrict__ wq,
                                            const float* __restrict__ wk,
                                            const float* __restrict__ wv,
                                            u16* xb, u16* wqT, u16* wkT, u16* wvT) {
    __shared__ float t[32][33];
    int bx = blockIdx.x, tid = threadIdx.x;
    if (bx < 4096) {                         // x: 1M float4 -> bf16
        int i = bx * 256 + tid;
        float4 v = ((const float4*)x)[i];
        u32 a = (u32)f2bf(v.x) | ((u32)f2bf(v.y) << 16);
        u32 b = (u32)f2bf(v.z) | ((u32)f2bf(v.w) << 16);
        ((uint2*)xb)[i] = make_uint2(a, b);
    } else if (bx < 8192) {                  // wq 2048x2048
        int b = bx - 4096;
        tr_f2b(wq, wqT, 2048, 2048, (b & 63) * 32, (b >> 6) * 32, t, tid);
    } else if (bx < 9216) {                  // wk 2048x512
        int b = bx - 8192;
        tr_f2b(wk, wkT, 2048, 512, (b & 15) * 32, (b >> 4) * 32, t, tid);
    } else {                                 // wv 2048x512
        int b = bx - 9216;
        tr_f2b(wv, wvT, 2048, 512, (b & 15) * 32, (b >> 4) * 32, t, tid);
    }
}

// ---------- m97-style bf16 GEMM core: Cb[M,N](bf16) = A[M,*] * BT[N,*]^T over k[ks,ke) ----------
__device__ __forceinline__ void gemm_core(const u16* __restrict__ A, const u16* __restrict__ BT,
                                          u16* Cb, int m0, int n0, int N, int Kstride,
                                          int ks, int ke) {
    __shared__ __align__(16) u16 As[128 * 32];
    __shared__ __align__(16) u16 Bs[128 * 32];
    const int tid = threadIdx.x, wave = tid >> 6, lane = tid & 63;
    const int quad = lane >> 4, l15 = lane & 15;
    const int wr = wave >> 1, wc = wave & 1;        // 64x64 per wave
    f32x4 acc[4][4] = {};
    for (int k0 = ks; k0 < ke; k0 += 32) {
        const u16* Ag = A + (size_t)m0 * Kstride + k0;
        const u16* Bg = BT + (size_t)n0 * Kstride + k0;
#pragma unroll
        for (int r2 = 0; r2 < 2; r2++) {
            int i = r2 * 256 + tid;                  // 16B chunk id; 4 chunks/row (BK=32)
            gl_lds16(Ag + (size_t)(i >> 2) * Kstride + (i & 3) * 8, &As[i * 8]);
            gl_lds16(Bg + (size_t)(i >> 2) * Kstride + (i & 3) * 8, &Bs[i * 8]);
        }
        __syncthreads();
        bf16x8 af[4], bfr[4];
#pragma unroll
        for (int i = 0; i < 4; i++) {
            af[i]  = ld_frag(&As[(wr * 64 + i * 16 + l15) * 32 + quad * 8]);
            bfr[i] = ld_frag(&Bs[(wc * 64 + i * 16 + l15) * 32 + quad * 8]);
        }
#pragma unroll
        for (int i = 0; i < 4; i++)
#pragma unroll
            for (int j = 0; j < 4; j++)
                acc[i][j] = mfma16(af[i], bfr[j], acc[i][j]);
        __syncthreads();
    }
#pragma unroll
    for (int i = 0; i < 4; i++)
#pragma unroll
        for (int r = 0; r < 4; r++) {
            u16* p = Cb + (size_t)(m0 + wr * 64 + i * 16 + quad * 4 + r) * N + n0 + wc * 64 + l15;
#pragma unroll
            for (int j = 0; j < 4; j++) p[j * 16] = f2bf(acc[i][j][r]);
        }
}

// fused Q/K/V projection, split-K=2: bf16 partials per z
__global__ __launch_bounds__(256) void gemm_proj(const u16* __restrict__ A,
                                                 const u16* __restrict__ wqT,
                                                 const u16* __restrict__ wkT,
                                                 const u16* __restrict__ wvT,
                                                 u16* Qp, u16* Kp, u16* Vp) {
    int bx = blockIdx.x, m0 = blockIdx.y * 128, z = blockIdx.z;
    int ks = z * 1024, ke = ks + 1024;
    if (bx < 16)      gemm_core(A, wqT, Qp + (size_t)z * 4194304, m0, bx * 128, 2048, 2048, ks, ke);
    else if (bx < 20) gemm_core(A, wkT, Kp + (size_t)z * 1048576, m0, (bx - 16) * 128, 512, 2048, ks, ke);
    else              gemm_core(A, wvT, Vp + (size_t)z * 1048576, m0, (bx - 20) * 128, 512, 2048, ks, ke);
}

// ---------- merged: Q partial merge + K/V partial merge + RoPE + wo transpose ----------
__global__ __launch_bounds__(256) void rope_combine(const u16* __restrict__ Qp,
                                                    const u16* __restrict__ Kp,
                                                    const u16* __restrict__ Vp,
                                                    const float* __restrict__ tc,
                                                    const float* __restrict__ tsn,
                                                    const float* __restrict__ wo,
                                                    u16* Qb, u16* Kb, u16* Vb, u16* woT) {
    __shared__ float t[32][33];
    int bx = blockIdx.x, tid = threadIdx.x;
    if (bx < 4096) {                         // Q: merge 2 bf16 partials (uint2 = 4 vals)
        int i = bx * 256 + tid;
        uint2 a = ((const uint2*)Qp)[i];
        uint2 b = ((const uint2*)(Qp + 4194304))[i];
        u32 r0_ = (u32)f2bf(bflo(a.x) + bflo(b.x)) | ((u32)f2bf(bfhi(a.x) + bfhi(b.x)) << 16);
        u32 r1_ = (u32)f2bf(bflo(a.y) + bflo(b.y)) | ((u32)f2bf(bfhi(a.y) + bfhi(b.y)) << 16);
        ((uint2*)Qb)[i] = make_uint2(r0_, r1_);
    } else if (bx < 6144) {                  // K: merge + rope -> bf16
        int s = bx - 4096, pr = tid, tt = pr & 31;
        float c = tc[s * 32 + tt], sn = tsn[s * 32 + tt];
        u32 a = ((const u32*)Kp)[s * 256 + pr];
        u32 b = ((const u32*)(Kp + 1048576))[s * 256 + pr];
        float e = bflo(a) + bflo(b), o = bfhi(a) + bfhi(b);
        ((u32*)Kb)[s * 256 + pr] = (u32)f2bf(e * c - o * sn) | ((u32)f2bf(e * sn + o * c) << 16);
    } else if (bx < 8192) {                  // V: merge + rope -> bf16 (row-major)
        int s = bx - 6144, pr = tid, tt = pr & 31;
        float c = tc[s * 32 + tt], sn = tsn[s * 32 + tt];
        u32 a = ((const u32*)Vp)[s * 256 + pr];
        u32 b = ((const u32*)(Vp + 1048576))[s * 256 + pr];
        float e = bflo(a) + bflo(b), o = bfhi(a) + bfhi(b);
        ((u32*)Vb)[s * 256 + pr] = (u32)f2bf(e * c - o * sn) | ((u32)f2bf(e * sn + o * c) << 16);
    } else {                                 // wo transpose 2048x2048
        int b = bx - 8192;
        tr_f2b(wo, woT, 2048, 2048, (b & 63) * 32, (b >> 6) * 32, t, tid);
    }
}

// bf16 (2048x512) -> bf16 transposed (512x2048)
__global__ __launch_bounds__(256) void transpose_b2b(const u16* __restrict__ in,
                                                     u16* __restrict__ out) {
    __shared__ u16 t[32][33];
    int tid = threadIdx.x, tx = tid & 31, ty = tid >> 5;
    int c0 = blockIdx.x * 32, r0 = blockIdx.y * 32;
    for (int i = ty; i < 32; i += 8)
        t[i][tx] = in[(size_t)(r0 + i) * 512 + c0 + tx];
    __syncthreads();
    for (int i = ty; i < 32; i += 8)
        out[(size_t)(c0 + i) * 2048 + r0 + tx] = t[tx][i];
}

// ---------- flash attention: GQA-shared K/V, 4 heads/block, BKV=64, no-max softmax ----------
// One block serves all 4 Q-heads of a kv-group: K/V staged ONCE per tile, K/V fragments
// shared across heads (4x MFMA per barrier vs per-head blocks). Q read direct global->frag.
// Grid: x = kvh (8), y = task (48, longest-first). 384 blocks, all co-resident at 2/CU.
#define LPK 72      // LDS row stride for 64-wide tiles (+8 pad: b128 reads 2-way max)
#define PSTR 1152   // per (head,wave) P block: 16 rows * LPK
#define T_(q,l,h) (((u32)(q) << 16) | ((u32)(l) << 8) | (u32)(h))
__device__ const u32 ATASK[48] = {
    T_(14,0,15), T_(15,0,16), T_(28,0,16), T_(29,0,16), T_(30,0,16), T_(31,0,16), T_(30,16,31), T_(31,16,32),
    T_(12,0,13), T_(13,0,14), T_(24,0,14), T_(25,0,14), T_(26,0,14), T_(27,0,14), T_(26,14,27), T_(27,14,28),
    T_(28,16,29), T_(29,16,30),
    T_(10,0,11), T_(11,0,12), T_(20,0,12), T_(21,0,12), T_(22,0,12), T_(23,0,12), T_(22,12,23), T_(23,12,24),
    T_(24,14,25), T_(25,14,26),
    T_(8,0,9), T_(9,0,10), T_(16,0,10), T_(17,0,10), T_(18,0,10), T_(19,0,10), T_(18,10,19), T_(19,10,20),
    T_(20,12,21), T_(21,12,22),
    T_(6,0,7), T_(7,0,8), T_(16,10,17), T_(17,10,18),
    T_(4,0,5), T_(5,0,6), T_(2,0,3), T_(3,0,4), T_(0,0,1), T_(1,0,2)
};

struct AttnSmem {
    u16 Ks[64 * LPK];        // [kv][d]
    u16 Vs[64 * LPK];        // [d][kv]  (V^T tile)
    u16 Ps[16 * PSTR];       // P staging: [head 0..3][wave 0..3][16 rows][LPK]
};

__global__ __launch_bounds__(256, 2) void attn_kernel(const u16* __restrict__ Qb,
                                                      const u16* __restrict__ Kb,
                                                      const u16* __restrict__ VbT,
                                                      u16* __restrict__ Yb,
                                                      float* __restrict__ Opart,
                                                      float* __restrict__ lpart) {
    __shared__ __align__(16) AttnSmem sm;
    const int tid = threadIdx.x, w = tid >> 6, lane = tid & 63;
    const int quad = lane >> 4, l15 = lane & 15;
    const int kvh = blockIdx.x, h_base = kvh * 4;
    const u32 tk = ATASK[blockIdx.y];
    const int qt = tk >> 16, lo = (tk >> 8) & 255, hi = tk & 255;
    const bool partial = (qt >= 16);
    const int pt = partial ? ((qt - 16) * 2 + (lo != 0)) : 0;
    const int q0 = qt * 64;
    const int qrow = q0 + w * 16 + quad * 4;   // + r

    // Q fragments: direct global loads (A-layout rows are 16B-contiguous in Qb)
    bf16x8 aQ[4][2];
    const u16* qp = Qb + (size_t)(q0 + w * 16 + l15) * 2048 + h_base * 64 + quad * 8;
#pragma unroll
    for (int hh = 0; hh < 4; hh++) {
        aQ[hh][0] = __builtin_bit_cast(bf16x8, *(const uint4*)(qp + hh * 64));
        aQ[hh][1] = __builtin_bit_cast(bf16x8, *(const uint4*)(qp + hh * 64 + 32));
    }

    f32x4 O[4][4] = {};
    float l_acc[4][4] = {};

    for (int jt = lo; jt < hi; jt++) {
        const int j0 = jt * 64;
        __syncthreads();
        const u16* Kg = Kb + (size_t)j0 * 512 + kvh * 64;
        const u16* Vg = VbT + (size_t)(kvh * 64) * 2048 + j0;
#pragma unroll
        for (int r2 = 0; r2 < 2; r2++) {
            int i = r2 * 256 + tid;          // 512 uint4 per tile
            *(uint4*)&sm.Ks[(i >> 3) * LPK + (i & 7) * 8] = *(const uint4*)(Kg + (size_t)(i >> 3) * 512 + (i & 7) * 8);
            *(uint4*)&sm.Vs[(i >> 3) * LPK + (i & 7) * 8] = *(const uint4*)(Vg + (size_t)(i >> 3) * 2048 + (i & 7) * 8);
        }
        __syncthreads();

        // K fragments, shared by all 4 heads
        bf16x8 bK[4][2];
#pragma unroll
        for (int j = 0; j < 4; j++) {
            bK[j][0] = ld_frag(&sm.Ks[(j * 16 + l15) * LPK + quad * 8]);
            bK[j][1] = ld_frag(&sm.Ks[(j * 16 + l15) * LPK + 32 + quad * 8]);
        }
        const bool diag = (jt == qt);
#pragma unroll
        for (int hh = 0; hh < 4; hh++) {
            f32x4 s[4];
#pragma unroll
            for (int j = 0; j < 4; j++) {
                f32x4 z = {};
                z = mfma16(aQ[hh][0], bK[j][0], z);
                z = mfma16(aQ[hh][1], bK[j][1], z);
                s[j] = z;
            }
            u16* Ph = &sm.Ps[(hh * 4 + w) * PSTR];
            if (diag) {
#pragma unroll
                for (int j = 0; j < 4; j++)
#pragma unroll
                    for (int r = 0; r < 4; r++) {
                        float p = __expf(s[j][r] * 0.125f);
                        if ((j0 + j * 16 + l15) > (qrow + r)) p = 0.f;
                        s[j][r] = p; l_acc[hh][r] += p;
                    }
            } else {
#pragma unroll
                for (int j = 0; j < 4; j++)
#pragma unroll
                    for (int r = 0; r < 4; r++) {
                        float p = __expf(s[j][r] * 0.125f);
                        s[j][r] = p; l_acc[hh][r] += p;
                    }
            }
#pragma unroll
            for (int j = 0; j < 4; j++)
#pragma unroll
                for (int r = 0; r < 4; r++)
                    Ph[(quad * 4 + r) * LPK + j * 16 + l15] = f2bf(s[j][r]);
        }
        // V fragments, shared by all 4 heads
        bf16x8 bV[4][2];
#pragma unroll
        for (int j = 0; j < 4; j++) {
            bV[j][0] = ld_frag(&sm.Vs[(j * 16 + l15) * LPK + quad * 8]);
            bV[j][1] = ld_frag(&sm.Vs[(j * 16 + l15) * LPK + 32 + quad * 8]);
        }
#pragma unroll
        for (int hh = 0; hh < 4; hh++) {
            const u16* Ph = &sm.Ps[(hh * 4 + w) * PSTR];
            bf16x8 aP0 = ld_frag(&Ph[l15 * LPK + quad * 8]);
            bf16x8 aP1 = ld_frag(&Ph[l15 * LPK + 32 + quad * 8]);
#pragma unroll
            for (int j = 0; j < 4; j++) {
                O[hh][j] = mfma16(aP0, bV[j][0], O[hh][j]);
                O[hh][j] = mfma16(aP1, bV[j][1], O[hh][j]);
            }
        }
    }
#pragma unroll
    for (int hh = 0; hh < 4; hh++) {
        const int h = h_base + hh;
        float l_i[4];
#pragma unroll
        for (int r = 0; r < 4; r++) {
            float rs = l_acc[hh][r];
            rs += __shfl_xor(rs, 1); rs += __shfl_xor(rs, 2);
            rs += __shfl_xor(rs, 4); rs += __shfl_xor(rs, 8);
            l_i[r] = rs;
        }
        if (!partial) {
#pragma unroll
            for (int r = 0; r < 4; r++) {
                float inv = __frcp_rn(l_i[r]);
#pragma unroll
                for (int j = 0; j < 4; j++)
                    Yb[(size_t)(q0 + w * 16 + quad * 4 + r) * 2048 + h * 64 + j * 16 + l15] =
                        f2bf(O[hh][j][r] * inv);
            }
        } else {
            float* Og = Opart + ((size_t)(pt * 32 + h) * 64) * 64;
#pragma unroll
            for (int r = 0; r < 4; r++) {
                int row = w * 16 + quad * 4 + r;
#pragma unroll
                for (int j = 0; j < 4; j++)
                    Og[(size_t)row * 64 + j * 16 + l15] = O[hh][j][r];
                if (l15 == 0) lpart[(size_t)(pt * 32 + h) * 64 + row] = l_i[r];
            }
        }
    }
}

// merge the two KV-split halves for q-tiles 16..31: O=(O0+O1)/(l0+l1)
__global__ void combine_kernel(const float* __restrict__ Opart,
                               const float* __restrict__ lpart,
                               u16* __restrict__ Yb) {
    int e = blockIdx.x * 256 + threadIdx.x;       // 524288 float4 elems
    int d4 = e & 15, h = (e >> 4) & 31, rg = e >> 9;   // rg in [0,1024)
    int t16 = rg >> 6, row = rg & 63;
    int s0 = (t16 * 2) * 32 + h, s1 = s0 + 32;
    float4 a = ((const float4*)Opart)[((size_t)s0 * 64 + row) * 16 + d4];
    float4 b = ((const float4*)Opart)[((size_t)s1 * 64 + row) * 16 + d4];
    float l = lpart[(size_t)s0 * 64 + row] + lpart[(size_t)s1 * 64 + row];
    float inv = __frcp_rn(l);
    u32 lo = (u32)f2bf((a.x + b.x) * inv) | ((u32)f2bf((a.y + b.y) * inv) << 16);
    u32 hi = (u32)f2bf((a.z + b.z) * inv) | ((u32)f2bf((a.w + b.w) * inv) << 16);
    int q = 1024 + rg;
    ((uint2*)(Yb + (size_t)q * 2048 + h * 64))[d4] = make_uint2(lo, hi);
}

// final projection, split-K=4, bf16 partials (non-contiguous scratch regions)
__global__ __launch_bounds__(256) void gemm_out_split(const u16* __restrict__ A,
                                                      const u16* __restrict__ BT,
                                                      u16* C0, u16* C1, u16* C2, u16* C3) {
    int z = blockIdx.z;
    u16* dst = z == 0 ? C0 : z == 1 ? C1 : z == 2 ? C2 : C3;
    gemm_core(A, BT, dst, blockIdx.y * 128, blockIdx.x * 128, 2048, 2048, z * 512, (z + 1) * 512);
}

__global__ void combine_out(const u16* __restrict__ C0, const u16* __restrict__ C1,
                            const u16* __restrict__ C2, const u16* __restrict__ C3,
                            float* __restrict__ out) {
    int i = blockIdx.x * 256 + threadIdx.x;        // 1M uint2 (4 bf16) -> float4
    uint2 a = ((const uint2*)C0)[i], b = ((const uint2*)C1)[i];
    uint2 c = ((const uint2*)C2)[i], d = ((const uint2*)C3)[i];
    float4 o;
    o.x = bflo(a.x) + bflo(b.x) + bflo(c.x) + bflo(d.x);
    o.y = bfhi(a.x) + bfhi(b.x) + bfhi(c.x) + bfhi(d.x);
    o.z = bflo(a.y) + bflo(b.y) + bflo(c.y) + bflo(d.y);
    o.w = bfhi(a.y) + bfhi(b.y) + bfhi(c.y) + bfhi(d.y);
    ((float4*)out)[i] = o;
}

extern "C" void kernel_launch(void* const* d_in, const int* in_sizes, int n_in,
                              void* d_out, int out_size, void* d_ws, size_t ws_size,
                              hipStream_t stream) {
    const float* x  = (const float*)d_in[0];
    const float* tc = (const float*)d_in[1];
    const float* ts = (const float*)d_in[2];
    const float* wq = (const float*)d_in[3];
    const float* wk = (const float*)d_in[4];
    const float* wv = (const float*)d_in[5];
    const float* wo = (const float*)d_in[6];
    float* out = (float*)d_out;

    char* w = (char*)d_ws;
    // Phase map (48 MiB):
    // A(prep):      xb@0-8  wqT@8-16  wkT@16-18  wvT@18-20
    // B(proj sk2):  Qp@20-36(bf16 z0/z1)  Kp@36-40  Vp@40-44
    // C(ropecomb):  Qb@0-8  woT@8-16  Kb@16-18  Vb@18-20 ; transpose: VbT@20-22
    // D(attn):      lpart@22  Yb@24-32  Opart@32-48
    // F(out sk4):   Cp z0@0-8 z1@16-24 z2@32-40 z3@40-48
    u16*   xb   = (u16*)(w);
    u16*   wqT  = (u16*)(w + (8u  << 20));
    u16*   wkT  = (u16*)(w + (16u << 20));
    u16*   wvT  = (u16*)(w + (18u << 20));
    u16*   Qp   = (u16*)(w + (20u << 20));
    u16*   Kp   = (u16*)(w + (36u << 20));
    u16*   Vp   = (u16*)(w + (40u << 20));
    u16*   Qb   = (u16*)(w);
    u16*   woT  = (u16*)(w + (8u  << 20));
    u16*   Kb   = (u16*)(w + (16u << 20));
    u16*   Vb   = (u16*)(w + (18u << 20));
    u16*   VbT  = (u16*)(w + (20u << 20));
    float* lpart= (float*)(w + (22u << 20));
    u16*   Yb   = (u16*)(w + (24u << 20));
    float* Opart= (float*)(w + (32u << 20));
    u16*   C0   = (u16*)(w);
    u16*   C1   = (u16*)(w + (16u << 20));
    u16*   C2   = (u16*)(w + (32u << 20));
    u16*   C3   = (u16*)(w + (40u << 20));

    prep<<<10240, 256, 0, stream>>>(x, wq, wk, wv, xb, wqT, wkT, wvT);
    gemm_proj<<<dim3(24, 16, 2), 256, 0, stream>>>(xb, wqT, wkT, wvT, Qp, Kp, Vp);
    rope_combine<<<12288, 256, 0, stream>>>(Qp, Kp, Vp, tc, ts, wo, Qb, Kb, Vb, woT);
    transpose_b2b<<<dim3(16, 64), 256, 0, stream>>>(Vb, VbT);
    attn_kernel<<<dim3(8, 48), 256, 0, stream>>>(Qb, Kb, VbT, Yb, Opart, lpart);
    combine_kernel<<<2048, 256, 0, stream>>>(Opart, lpart, Yb);
    gemm_out_split<<<dim3(16, 16, 4), 256, 0, stream>>>(Yb, woT, C0, C1, C2, C3);
    combine_out<<<4096, 256, 0, stream>>>(C0, C1, C2, C3, out);
}